// Round 9
// baseline (285.524 us; speedup 1.0000x reference)
//
#include <hip/hip_runtime.h>

constexpr int N_NODES = 100000;
constexpr int N_FEAT  = 512;
constexpr int N_EDGES = 1600000;

// fixed-point packing for LDS u64 accumulation
constexpr float FXS = 1048576.0f;  // 2^20
constexpr float FXB = 32.0f;       // positivity bias; FXB*FXS = 2^25 exact

// binning (round-8 lesson: keep binning NARROW; round-7 lesson: no idle CUs)
constexpr int BSH   = 8;
constexpr int BINW  = 1 << BSH;                     // 256 nodes/bin
constexpr int NBINS = (N_NODES + BINW - 1) >> BSH;  // 391
constexpr int BCAP  = 5120;  // bin load: mean 4096, +16 sigma
constexpr int NBB   = 500;   // binning blocks (then they join stealing)
constexpr int CHUNK = N_EDGES / NBB;                // 3200 (exact)
constexpr int GRID  = 2048;

// wave-level row work-stealing
constexpr int ROWCH  = 16;                          // rows per steal chunk (4 iters)
constexpr int NCHUNK = N_NODES / ROWCH;             // 6250 (exact)
constexpr int NDISP  = 16;                          // dispenser counters
constexpr int RSZ    = (NCHUNK + NDISP - 1) / NDISP; // 391 chunks/region

typedef float vfloat4 __attribute__((ext_vector_type(4)));

// ws float offsets
constexpr int WS_W    = 0;                    // [0,1024) two cols of w1@w2
constexpr int WS_C    = 1024;                 // c (pad to 1056)
constexpr int WS_CUR  = 1056;                 // NBINS cursors + NDISP dispensers (pad 512)
constexpr int WS_DEG  = WS_CUR + 512;         // deg[N] int
constexpr int WS_DINV = WS_DEG + N_NODES;     // dinv[N]
constexpr int WS_G    = WS_DINV + N_NODES;    // g[N,2] (byte%8==0)
constexpr int WS_FXP  = WS_G + 2 * N_NODES;   // u64[N] packed addends
constexpr int WS_BINS = WS_FXP + 2 * N_NODES; // u32[NBINS*BCAP] ~8MB

static_assert((WS_FXP * 4) % 8 == 0, "fxp alignment");
static_assert(N_NODES % ROWCH == 0, "");
static_assert(NBINS + NDISP <= 512, "");

// ---- kernel 1: W = w1@w2, c = b1@w2+b2, zero cursors+dispensers ----
__global__ void k_prep(const float* __restrict__ w1, const float* __restrict__ w2,
                       const float* __restrict__ b1, const float* __restrict__ b2,
                       float* __restrict__ ws) {
    int i = blockIdx.x * blockDim.x + threadIdx.x;
    if (i < NBINS + NDISP) reinterpret_cast<int*>(ws + WS_CUR)[i] = 0;
    if (i < N_FEAT) {
        float a0 = 0.f, a1 = 0.f;
        for (int m = 0; m < 128; ++m) {
            float w = w1[i * 128 + m];
            a0 += w * w2[m * 2 + 0];
            a1 += w * w2[m * 2 + 1];
        }
        ws[WS_W + i] = a0;
        ws[WS_W + 512 + i] = a1;
        if (i < 2) {
            float s = b2[i];
            for (int m = 0; m < 128; ++m) s += b1[m] * w2[m * 2 + i];
            ws[WS_C + i] = s;
        }
    }
}

// ---- kernel 2: blocks [0,NBB) bin their edge chunk, then ALL blocks
//      row-dot via wave-level work stealing (no idle CUs, no stragglers) ----
__global__ __launch_bounds__(256) void k_fused(
    const float* __restrict__ x, float* __restrict__ ws,
    const int* __restrict__ src, const int* __restrict__ dst,
    float2* __restrict__ g) {
    int b = blockIdx.x;
    int tid = threadIdx.x;
    int* gcur = reinterpret_cast<int*>(ws + WS_CUR);

    if (b < NBB) {
        // --- binning: count -> reserve -> place; edge packed into one u32 ---
        __shared__ int cnt[NBINS];
        __shared__ int offs[NBINS];
        __shared__ int cur2[NBINS];
        for (int i = tid; i < NBINS; i += 256) { cnt[i] = 0; cur2[i] = 0; }
        __syncthreads();
        int base = b * CHUNK;
        for (int e = base + tid; e < base + CHUNK; e += 256)
            atomicAdd(&cnt[dst[e] >> BSH], 1);
        __syncthreads();
        for (int i = tid; i < NBINS; i += 256) {
            int c = cnt[i];
            int pos = c ? atomicAdd(&gcur[i], c) : 0;
            offs[i] = i * BCAP + pos;
        }
        __syncthreads();
        unsigned int* bins = reinterpret_cast<unsigned int*>(ws + WS_BINS);
        for (int e = base + tid; e < base + CHUNK; e += 256) {
            int d = dst[e], s = src[e];
            int bin = d >> BSH;
            int r = atomicAdd(&cur2[bin], 1);
            bins[offs[bin] + r] = (unsigned int)s | ((unsigned int)(d & (BINW - 1)) << 17);
        }
        // fall through into row-stealing (LDS no longer needed)
    }

    // --- rowdot via stealing: 16-row chunks, 16 lanes per row ---
    const vfloat4* W0q = reinterpret_cast<const vfloat4*>(ws + WS_W);
    const vfloat4* W1q = reinterpret_cast<const vfloat4*>(ws + WS_W + 512);
    int lane = tid & 63;
    int wave = tid >> 6;
    int j = lane & 15, i4 = lane >> 4;

    vfloat4 w0[8], w1[8];
    #pragma unroll
    for (int k = 0; k < 8; ++k) {
        w0[k] = W0q[k * 16 + j];
        w1[k] = W1q[k * 16 + j];
    }

    int* disp = gcur + NBINS;                 // 16 dispensers
    int d0 = (b * 4 + wave) & (NDISP - 1);
    for (int t = 0; t < NDISP; ++t) {
        int d = (d0 + t) & (NDISP - 1);
        int rbase = d * RSZ;
        int rend  = min(rbase + RSZ, NCHUNK);
        // cheap non-atomic pre-check so the final sweep is load-only
        int seen = 0;
        if (lane == 0)
            seen = __hip_atomic_load(&disp[d], __ATOMIC_RELAXED, __HIP_MEMORY_SCOPE_AGENT);
        seen = __shfl(seen, 0);
        if (rbase + seen >= rend) continue;
        while (true) {
            int c = 0;
            if (lane == 0) c = atomicAdd(&disp[d], 1);
            c = __shfl(c, 0);
            int chunk = rbase + c;
            if (chunk >= rend) break;
            #pragma unroll
            for (int it = 0; it < 4; ++it) {
                int row = chunk * ROWCH + it * 4 + i4;
                const vfloat4* xr = reinterpret_cast<const vfloat4*>(x + (size_t)row * N_FEAT);
                vfloat4 xv[8];
                #pragma unroll
                for (int k = 0; k < 8; ++k)
                    xv[k] = __builtin_nontemporal_load(&xr[k * 16 + j]);
                float a0 = 0.f, a1 = 0.f;
                #pragma unroll
                for (int k = 0; k < 8; ++k) {
                    a0 += xv[k].x*w0[k].x + xv[k].y*w0[k].y + xv[k].z*w0[k].z + xv[k].w*w0[k].w;
                    a1 += xv[k].x*w1[k].x + xv[k].y*w1[k].y + xv[k].z*w1[k].z + xv[k].w*w1[k].w;
                }
                #pragma unroll
                for (int off = 1; off <= 8; off <<= 1) {
                    a0 += __shfl_xor(a0, off);
                    a1 += __shfl_xor(a1, off);
                }
                if (j == 0) g[row] = make_float2(a0, a1);
            }
        }
    }
}

// ---- kernel 3: per-bin degree count; write deg, dinv, packed addend fxp ----
__global__ __launch_bounds__(256) void k_deg(float* __restrict__ ws) {
    int b = blockIdx.x;
    const int* gcur = reinterpret_cast<const int*>(ws + WS_CUR);
    const unsigned int* bins = reinterpret_cast<const unsigned int*>(ws + WS_BINS) + b * BCAP;
    int n = min(gcur[b], BCAP);
    __shared__ int cnt[BINW];
    cnt[threadIdx.x] = 0;
    __syncthreads();
    for (int i = threadIdx.x; i < n; i += 256)
        atomicAdd(&cnt[bins[i] >> 17], 1);
    __syncthreads();
    int d = (b << BSH) + threadIdx.x;
    if (d < N_NODES) {
        int dg = cnt[threadIdx.x] + 1;               // + self-loop
        reinterpret_cast<int*>(ws + WS_DEG)[d] = dg;
        float di = rsqrtf((float)dg);
        ws[WS_DINV + d] = di;
        float2 gv = reinterpret_cast<const float2*>(ws + WS_G)[d];
        unsigned int lo = (unsigned int)__float2int_rn((gv.x * di + FXB) * FXS);
        unsigned int hi = (unsigned int)__float2int_rn((gv.y * di + FXB) * FXS);
        reinterpret_cast<unsigned long long*>(ws + WS_FXP)[d] =
            ((unsigned long long)hi << 32) | (unsigned long long)lo;
    }
}

// ---- kernel 4: per-bin LDS u64 accumulation of fxp[src]; finalize ----
__global__ __launch_bounds__(256) void k_pass2(float* __restrict__ ws,
                                               float2* __restrict__ out) {
    int b = blockIdx.x;
    const int* gcur = reinterpret_cast<const int*>(ws + WS_CUR);
    const unsigned int* bins = reinterpret_cast<const unsigned int*>(ws + WS_BINS) + b * BCAP;
    const int* deg = reinterpret_cast<const int*>(ws + WS_DEG);
    const float* dinv = ws + WS_DINV;
    const unsigned long long* fxp = reinterpret_cast<const unsigned long long*>(ws + WS_FXP);
    int n = min(gcur[b], BCAP);
    __shared__ unsigned long long acc[BINW];
    acc[threadIdx.x] = 0ull;
    __syncthreads();
    for (int i = threadIdx.x; i < n; i += 256) {
        unsigned int p = bins[i];
        atomicAdd(&acc[p >> 17], fxp[p & 0x1FFFFu]);
    }
    __syncthreads();
    int d = (b << BSH) + threadIdx.x;
    if (d < N_NODES) {
        unsigned long long a = acc[threadIdx.x] + fxp[d];   // + self-loop addend
        long long dg = (long long)deg[d];
        long long bias = dg << 25;                           // exact: deg * FXB*FXS
        long long lo = (long long)(a & 0xFFFFFFFFull) - bias;
        long long hi = (long long)(a >> 32) - bias;
        float di = dinv[d];
        out[d] = make_float2(di * ((float)lo * (1.0f / FXS)) + ws[WS_C + 0],
                             di * ((float)hi * (1.0f / FXS)) + ws[WS_C + 1]);
    }
}

extern "C" void kernel_launch(void* const* d_in, const int* in_sizes, int n_in,
                              void* d_out, int out_size, void* d_ws, size_t ws_size,
                              hipStream_t stream) {
    const float* x  = (const float*)d_in[0];
    const float* w1 = (const float*)d_in[1];
    const float* b1 = (const float*)d_in[2];
    const float* w2 = (const float*)d_in[3];
    const float* b2 = (const float*)d_in[4];
    const int*   ei = (const int*)d_in[5];   // [2, E]: src row then dst row
    float* ws = (float*)d_ws;

    float2* g = (float2*)(ws + WS_G);

    k_prep<<<2, 256, 0, stream>>>(w1, w2, b1, b2, ws);
    k_fused<<<GRID, 256, 0, stream>>>(x, ws, ei, ei + N_EDGES, g);
    k_deg<<<NBINS, 256, 0, stream>>>(ws);
    k_pass2<<<NBINS, 256, 0, stream>>>(ws, (float2*)d_out);
}

// Round 10
// 86.717 us; speedup vs baseline: 3.2926x; 3.2926x over previous
//
#include <hip/hip_runtime.h>

constexpr int N_NODES = 100000;
constexpr int N_FEAT  = 512;
constexpr int N_EDGES = 1600000;

// fixed-point packing for LDS u64 accumulation
constexpr float FXS = 1048576.0f;  // 2^20
constexpr float FXB = 32.0f;       // positivity bias; FXB*FXS = 2^25 exact

// binning (R8: keep binning NARROW; R9: no dynamic scheduling on critical path)
constexpr int BSH   = 8;
constexpr int BINW  = 1 << BSH;                     // 256 nodes/bin
constexpr int NBINS = (N_NODES + BINW - 1) >> BSH;  // 391
constexpr int BCAP  = 5120;  // bin load: mean 4096, +16 sigma
constexpr int NBB   = 500;   // binning blocks
constexpr int CHUNK = N_EDGES / NBB;                // 3200 (exact)
constexpr int GRID  = 2048;
constexpr int NPURE = GRID - NBB;                   // 1548

// exact weighted static rowdot partition (quad = 4 rows):
//   pure blocks p<424: 13 quads each  -> [0, 5512)
//   pure blocks p>=424: 12 quads each -> [5512, 19000)
//   binning blocks: 12 quads each     -> [19000, 25000)   (binning ~ 1 quad-equiv)
constexpr int NQ     = N_NODES / 4;                 // 25000
constexpr int PSPLIT = 424;
static_assert(PSPLIT * 13 + (NPURE - PSPLIT) * 12 + NBB * 12 == NQ, "exact cover");

typedef float vfloat4 __attribute__((ext_vector_type(4)));

// ws float offsets
constexpr int WS_W    = 0;                    // [0,1024) two cols of w1@w2
constexpr int WS_C    = 1024;                 // c (pad to 1056)
constexpr int WS_CUR  = 1056;                 // NBINS cursors (pad 512)
constexpr int WS_DEG  = WS_CUR + 512;         // deg[N] int
constexpr int WS_DINV = WS_DEG + N_NODES;     // dinv[N]
constexpr int WS_G    = WS_DINV + N_NODES;    // g[N,2] (byte%8==0)
constexpr int WS_FXP  = WS_G + 2 * N_NODES;   // u64[N] packed addends
constexpr int WS_BINS = WS_FXP + 2 * N_NODES; // u32[NBINS*BCAP] ~8MB

static_assert((WS_FXP * 4) % 8 == 0, "fxp alignment");
static_assert(N_NODES % 4 == 0, "");

// ---- kernel 1: W = w1@w2, c = b1@w2+b2, zero cursors ----
__global__ void k_prep(const float* __restrict__ w1, const float* __restrict__ w2,
                       const float* __restrict__ b1, const float* __restrict__ b2,
                       float* __restrict__ ws) {
    int i = blockIdx.x * blockDim.x + threadIdx.x;
    if (i < NBINS) reinterpret_cast<int*>(ws + WS_CUR)[i] = 0;
    if (i < N_FEAT) {
        float a0 = 0.f, a1 = 0.f;
        for (int m = 0; m < 128; ++m) {
            float w = w1[i * 128 + m];
            a0 += w * w2[m * 2 + 0];
            a1 += w * w2[m * 2 + 1];
        }
        ws[WS_W + i] = a0;
        ws[WS_W + 512 + i] = a1;
        if (i < 2) {
            float s = b2[i];
            for (int m = 0; m < 128; ++m) s += b1[m] * w2[m * 2 + i];
            ws[WS_C + i] = s;
        }
    }
}

// ---- kernel 2: blocks [0,NBB) bin 3200 edges then rowdot 12 quads;
//      pure blocks rowdot 12-13 quads. Exact static cover, no idle CUs. ----
__global__ __launch_bounds__(256) void k_fused(
    const float* __restrict__ x, float* __restrict__ ws,
    const int* __restrict__ src, const int* __restrict__ dst,
    float2* __restrict__ g) {
    int b = blockIdx.x;
    int tid = threadIdx.x;
    int* gcur = reinterpret_cast<int*>(ws + WS_CUR);

    int qbase, qcnt;
    if (b < NBB) {
        qbase = 19000 + 12 * b;  qcnt = 12;
        // --- binning: count -> reserve -> place; edge packed into one u32 ---
        __shared__ int cnt[NBINS];
        __shared__ int offs[NBINS];
        __shared__ int cur2[NBINS];
        for (int i = tid; i < NBINS; i += 256) { cnt[i] = 0; cur2[i] = 0; }
        __syncthreads();
        int base = b * CHUNK;
        for (int e = base + tid; e < base + CHUNK; e += 256)
            atomicAdd(&cnt[dst[e] >> BSH], 1);
        __syncthreads();
        for (int i = tid; i < NBINS; i += 256) {
            int c = cnt[i];
            int pos = c ? atomicAdd(&gcur[i], c) : 0;
            offs[i] = i * BCAP + pos;
        }
        __syncthreads();
        unsigned int* bins = reinterpret_cast<unsigned int*>(ws + WS_BINS);
        for (int e = base + tid; e < base + CHUNK; e += 256) {
            int d = dst[e], s = src[e];
            int bin = d >> BSH;
            int r = atomicAdd(&cur2[bin], 1);
            bins[offs[bin] + r] = (unsigned int)s | ((unsigned int)(d & (BINW - 1)) << 17);
        }
        // fall through into rowdot (LDS no longer needed)
    } else {
        int p = b - NBB;
        if (p < PSPLIT) { qbase = 13 * p;        qcnt = 13; }
        else            { qbase = 12 * p + 424;  qcnt = 12; }
    }

    // --- rowdot: 4 rows per quad, 16 lanes per row ---
    const vfloat4* W0q = reinterpret_cast<const vfloat4*>(ws + WS_W);
    const vfloat4* W1q = reinterpret_cast<const vfloat4*>(ws + WS_W + 512);
    int lane = tid & 63;
    int wave = tid >> 6;
    int j = lane & 15, i4 = lane >> 4;

    vfloat4 w0[8], w1[8];
    #pragma unroll
    for (int k = 0; k < 8; ++k) {
        w0[k] = W0q[k * 16 + j];
        w1[k] = W1q[k * 16 + j];
    }

    for (int q = qbase + wave; q < qbase + qcnt; q += 4) {
        int row = q * 4 + i4;
        const vfloat4* xr = reinterpret_cast<const vfloat4*>(x + (size_t)row * N_FEAT);
        vfloat4 xv[8];
        #pragma unroll
        for (int k = 0; k < 8; ++k)
            xv[k] = __builtin_nontemporal_load(&xr[k * 16 + j]);
        float a0 = 0.f, a1 = 0.f;
        #pragma unroll
        for (int k = 0; k < 8; ++k) {
            a0 += xv[k].x*w0[k].x + xv[k].y*w0[k].y + xv[k].z*w0[k].z + xv[k].w*w0[k].w;
            a1 += xv[k].x*w1[k].x + xv[k].y*w1[k].y + xv[k].z*w1[k].z + xv[k].w*w1[k].w;
        }
        #pragma unroll
        for (int off = 1; off <= 8; off <<= 1) {
            a0 += __shfl_xor(a0, off);
            a1 += __shfl_xor(a1, off);
        }
        if (j == 0) g[row] = make_float2(a0, a1);
    }
}

// ---- kernel 3: per-bin degree count; write deg, dinv, packed addend fxp ----
__global__ __launch_bounds__(256) void k_deg(float* __restrict__ ws) {
    int b = blockIdx.x;
    const int* gcur = reinterpret_cast<const int*>(ws + WS_CUR);
    const unsigned int* bins = reinterpret_cast<const unsigned int*>(ws + WS_BINS) + b * BCAP;
    int n = min(gcur[b], BCAP);
    __shared__ int cnt[BINW];
    cnt[threadIdx.x] = 0;
    __syncthreads();
    for (int i = threadIdx.x; i < n; i += 256)
        atomicAdd(&cnt[bins[i] >> 17], 1);
    __syncthreads();
    int d = (b << BSH) + threadIdx.x;
    if (d < N_NODES) {
        int dg = cnt[threadIdx.x] + 1;               // + self-loop
        reinterpret_cast<int*>(ws + WS_DEG)[d] = dg;
        float di = rsqrtf((float)dg);
        ws[WS_DINV + d] = di;
        float2 gv = reinterpret_cast<const float2*>(ws + WS_G)[d];
        unsigned int lo = (unsigned int)__float2int_rn((gv.x * di + FXB) * FXS);
        unsigned int hi = (unsigned int)__float2int_rn((gv.y * di + FXB) * FXS);
        reinterpret_cast<unsigned long long*>(ws + WS_FXP)[d] =
            ((unsigned long long)hi << 32) | (unsigned long long)lo;
    }
}

// ---- kernel 4: per-bin LDS u64 accumulation of fxp[src]; finalize ----
__global__ __launch_bounds__(256) void k_pass2(float* __restrict__ ws,
                                               float2* __restrict__ out) {
    int b = blockIdx.x;
    const int* gcur = reinterpret_cast<const int*>(ws + WS_CUR);
    const unsigned int* bins = reinterpret_cast<const unsigned int*>(ws + WS_BINS) + b * BCAP;
    const int* deg = reinterpret_cast<const int*>(ws + WS_DEG);
    const float* dinv = ws + WS_DINV;
    const unsigned long long* fxp = reinterpret_cast<const unsigned long long*>(ws + WS_FXP);
    int n = min(gcur[b], BCAP);
    __shared__ unsigned long long acc[BINW];
    acc[threadIdx.x] = 0ull;
    __syncthreads();
    for (int i = threadIdx.x; i < n; i += 256) {
        unsigned int p = bins[i];
        atomicAdd(&acc[p >> 17], fxp[p & 0x1FFFFu]);
    }
    __syncthreads();
    int d = (b << BSH) + threadIdx.x;
    if (d < N_NODES) {
        unsigned long long a = acc[threadIdx.x] + fxp[d];   // + self-loop addend
        long long dg = (long long)deg[d];
        long long bias = dg << 25;                           // exact: deg * FXB*FXS
        long long lo = (long long)(a & 0xFFFFFFFFull) - bias;
        long long hi = (long long)(a >> 32) - bias;
        float di = dinv[d];
        out[d] = make_float2(di * ((float)lo * (1.0f / FXS)) + ws[WS_C + 0],
                             di * ((float)hi * (1.0f / FXS)) + ws[WS_C + 1]);
    }
}

extern "C" void kernel_launch(void* const* d_in, const int* in_sizes, int n_in,
                              void* d_out, int out_size, void* d_ws, size_t ws_size,
                              hipStream_t stream) {
    const float* x  = (const float*)d_in[0];
    const float* w1 = (const float*)d_in[1];
    const float* b1 = (const float*)d_in[2];
    const float* w2 = (const float*)d_in[3];
    const float* b2 = (const float*)d_in[4];
    const int*   ei = (const int*)d_in[5];   // [2, E]: src row then dst row
    float* ws = (float*)d_ws;

    float2* g = (float2*)(ws + WS_G);

    k_prep<<<2, 256, 0, stream>>>(w1, w2, b1, b2, ws);
    k_fused<<<GRID, 256, 0, stream>>>(x, ws, ei, ei + N_EDGES, g);
    k_deg<<<NBINS, 256, 0, stream>>>(ws);
    k_pass2<<<NBINS, 256, 0, stream>>>(ws, (float2*)d_out);
}